// Round 4
// baseline (185.870 us; speedup 1.0000x reference)
//
#include <hip/hip_runtime.h>

// ROI Align (FPN, PH=PW=7, SR=2), fp32 I/O.
// R13 = R12 RESUBMIT (previous bench died on container acquisition, not on
// the kernel: no compile/correctness signal was produced; load patterns and
// swizzle are identical-or-narrower vs the R11 kernel that passed).
// R12 = R11 schedule (channel-outer/roi-inner + chunked XCD swizzle, FETCH
// 192->49MB ~= compulsory) + lane-slot reduction.
// Model (R9/R10/R11): three kernels with FETCH varying 4x and waves/CU 2.4x
// all land 69-74us. Invariant = divergent-gather LANE count: 25.7M 16B
// lane-loads (33.5M slots at 49/64 active) ~ 131K cy/CU at ~1 addr/cy =
// 55us ~= the floor. Bound: per-CU vector-memory address processing.
// Fixes (both keep the R11 schedule):
//  1) full 64-lane packing: wave = one roi, lanes = 64 (c2,px) pairs
//     (49x64=3136 pairs = exactly 49 waves/roi). k stays wave-uniform;
//     stores become lane-contiguous (kills the 32.4 vs 25.1MB write amp).
//  2) row-dedup: when rA[0]==rA[1] (small bh, ~50% of lanes) the sy=1
//     row pair equals sy=0's -> exec-masked skip of those gathers.
// Predicted: dur 69 -> ~48-56us, WRITE -> ~25.3MB, FETCH ~50MB unchanged.
// Rule: <10% gain => model wrong => LDS staging + TA counters next.

#define NUM_CH 256
#define CPT    4            // channels per thread
#define CGRP   64           // NUM_CH / CPT
#define WPR    49           // waves per roi (CGRP*49/64)
#define PAIRS  3136         // CGRP*49

typedef float floatx2 __attribute__((ext_vector_type(2)));
typedef float floatx4 __attribute__((ext_vector_type(4)));

__device__ __forceinline__ float ext4(floatx4 v, int i) {
    float r = (i == 1) ? v.y : v.x;
    r = (i == 2) ? v.z : r;
    r = (i == 3) ? v.w : r;
    return r;
}

__global__ __launch_bounds__(256) void roi_align_kernel(
    const float* __restrict__ f0,
    const float* __restrict__ f1,
    const float* __restrict__ f2,
    const float* __restrict__ f3,
    const float* __restrict__ rois_f,
    const int* __restrict__ level,
    float* __restrict__ out,
    int K,                           // number of rois
    int NW)                          // total waves = K * WPR
{
    // ---- chunked XCD swizzle (R11): contiguous logical range per XCD ------
    int nb  = gridDim.x;
    int q   = nb >> 3, r = nb & 7;
    int xcd = blockIdx.x & 7;
    int idx = blockIdx.x >> 3;
    int l   = xcd * q + min(xcd, r) + idx;          // bijective for any nb

    int wid = l * 4 + (int)(threadIdx.x >> 6);      // logical wave id
    if (wid >= NW) return;
    int lane = threadIdx.x & 63;

    int k = wid % K;                                // roi        (inner)
    int g = wid / K;                                // pair-group (outer)
    k = __builtin_amdgcn_readfirstlane(k);          // wave-uniform -> SGPR
    g = __builtin_amdgcn_readfirstlane(g);

    int pair = g * 64 + lane;                       // 0..3135, all lanes live
    int c2   = pair / 49;                           // channel group (per-lane)
    int p    = pair - c2 * 49;                      // output pixel
    int ph = p / 7;
    int pw = p % 7;

    int lvl = level[k];
    const float* f;
    int H, W; float scale;
    if (lvl == 0)      { f = f0; H = 200; W = 200; scale = 0.25f;    }
    else if (lvl == 1) { f = f1; H = 100; W = 100; scale = 0.125f;   }
    else if (lvl == 2) { f = f2; H = 50;  W = 50;  scale = 0.0625f;  }
    else               { f = f3; H = 25;  W = 25;  scale = 0.03125f; }

    const float* rf = rois_f + (size_t)k * 5;
    float r0 = rf[0];
    float x1 = rf[1] * scale, y1 = rf[2] * scale;
    float x2 = rf[3] * scale, y2 = rf[4] * scale;
    int bi = (int)r0;
    bi = (bi < 0) ? 0 : ((bi > 1) ? 1 : bi);

    float bh = fmaxf(y2 - y1, 1.0f) * (1.0f / 7.0f);
    float bw = fmaxf(x2 - x1, 1.0f) * (1.0f / 7.0f);

    const size_t plane = (size_t)(H * W);
    const float* base  = f + ((size_t)bi * NUM_CH + c2) * plane;
    const size_t cstr  = (size_t)CGRP * plane;   // stride between my channels

    // ---- factored geometry: 2 y-samples + 2 x-samples (channel-invariant) -
    int   rA[2], rB[2];
    float lyv[2], hyv[2], vy[2];
    #pragma unroll
    for (int sy = 0; sy < 2; ++sy) {
        float y = y1 + (float)ph * bh + ((float)sy + 0.5f) * (bh * 0.5f);
        bool valid = (y > -1.0f) && (y < (float)H);
        float yc = fmaxf(y, 0.0f);
        int yl = min((int)yc, H - 1);
        int yh = min(yl + 1, H - 1);
        float ly = (yl >= H - 1) ? 0.0f : (yc - (float)yl);
        rA[sy] = yl * W;
        rB[sy] = yh * W;
        lyv[sy] = ly; hyv[sy] = 1.0f - ly;
        vy[sy] = valid ? 0.25f : 0.0f;     // fold 2x2 mean into y validity
    }
    int   xlv[2], xhv[2];
    float lxv[2], hxv[2], vx[2];
    #pragma unroll
    for (int sx = 0; sx < 2; ++sx) {
        float x = x1 + (float)pw * bw + ((float)sx + 0.5f) * (bw * 0.5f);
        bool valid = (x > -1.0f) && (x < (float)W);
        float xc = fmaxf(x, 0.0f);
        int xl = min((int)xc, W - 1);
        float lx = (xl >= W - 1) ? 0.0f : (xc - (float)xl);
        xlv[sx] = xl;
        xhv[sx] = min(xl + 1, W - 1);
        lxv[sx] = lx; hxv[sx] = 1.0f - lx;
        vx[sx] = valid ? 1.0f : 0.0f;
    }

    // row-dedup: yl equal => yh equal => whole sy=1 row pair duplicates sy=0
    bool same = (rA[1] == rA[0]);

    float acc[CPT];
    #pragma unroll
    for (int j = 0; j < CPT; ++j) acc[j] = 0.0f;

    if (bw <= 3.98f) {
        // ---- merged path: x-span of all 4 x-corners fits a 4-float window -
        int xq = min(xlv[0], W - 4);               // window base (>=0: W>=25)
        int i0l = min(max(xlv[0] - xq, 0), 3);
        int i0h = min(max(xhv[0] - xq, 0), 3);
        int i1l = min(max(xlv[1] - xq, 0), 3);
        int i1h = min(max(xhv[1] - xq, 0), 3);

        floatx4 LA[CPT], LB[CPT];
        #pragma unroll
        for (int j = 0; j < CPT; ++j) {
            const float* bj = base + (size_t)j * cstr;
            LA[j] = *(const floatx4*)(bj + rA[0] + xq);
            LB[j] = *(const floatx4*)(bj + rB[0] + xq);
        }
        #pragma unroll
        for (int sy = 0; sy < 2; ++sy) {
            if (sy == 1 && !same) {
                // reload row pair only where it actually changed (exec-masked
                // for 'same' lanes -> no address slots spent there)
                #pragma unroll
                for (int j = 0; j < CPT; ++j) {
                    const float* bj = base + (size_t)j * cstr;
                    LA[j] = *(const floatx4*)(bj + rA[1] + xq);
                    LB[j] = *(const floatx4*)(bj + rB[1] + xq);
                }
            }
            #pragma unroll
            for (int sx = 0; sx < 2; ++sx) {
                int il = sx ? i1l : i0l;
                int ih = sx ? i1h : i0h;
                float vs  = vy[sy] * vx[sx];
                float w00 = hyv[sy] * hxv[sx] * vs;
                float w01 = hyv[sy] * lxv[sx] * vs;
                float w10 = lyv[sy] * hxv[sx] * vs;
                float w11 = lyv[sy] * lxv[sx] * vs;
                #pragma unroll
                for (int j = 0; j < CPT; ++j) {
                    acc[j] += w00 * ext4(LA[j], il) + w01 * ext4(LA[j], ih)
                            + w10 * ext4(LB[j], il) + w11 * ext4(LB[j], ih);
                }
            }
        }
    } else {
        // ---- wide-ROI path: dwordx2 gathers, sy=1 reload only if needed ---
        int   xb[2];
        float sel[2];
        #pragma unroll
        for (int sx = 0; sx < 2; ++sx) {
            int xq = min(xlv[sx], W - 2);
            xb[sx]  = xq;
            sel[sx] = (xlv[sx] > xq) ? 1.0f : 0.0f;
        }
        floatx2 va[CPT][2], vb[CPT][2];
        #pragma unroll
        for (int sx = 0; sx < 2; ++sx) {
            #pragma unroll
            for (int j = 0; j < CPT; ++j) {
                const float* bj = base + (size_t)j * cstr;
                va[j][sx] = *(const floatx2*)(bj + rA[0] + xb[sx]);
                vb[j][sx] = *(const floatx2*)(bj + rB[0] + xb[sx]);
            }
        }
        #pragma unroll
        for (int sy = 0; sy < 2; ++sy) {
            if (sy == 1 && !same) {
                #pragma unroll
                for (int sx = 0; sx < 2; ++sx) {
                    #pragma unroll
                    for (int j = 0; j < CPT; ++j) {
                        const float* bj = base + (size_t)j * cstr;
                        va[j][sx] = *(const floatx2*)(bj + rA[1] + xb[sx]);
                        vb[j][sx] = *(const floatx2*)(bj + rB[1] + xb[sx]);
                    }
                }
            }
            #pragma unroll
            for (int sx = 0; sx < 2; ++sx) {
                float vs  = vy[sy] * vx[sx];
                float w00 = hyv[sy] * hxv[sx] * vs;
                float w01 = hyv[sy] * lxv[sx] * vs;
                float w10 = lyv[sy] * hxv[sx] * vs;
                float w11 = lyv[sy] * lxv[sx] * vs;
                float s0  = sel[sx];
                #pragma unroll
                for (int j = 0; j < CPT; ++j) {
                    float v00 = va[j][sx].x + s0 * (va[j][sx].y - va[j][sx].x);
                    float v10 = vb[j][sx].x + s0 * (vb[j][sx].y - vb[j][sx].x);
                    acc[j] += w00 * v00 + w01 * va[j][sx].y
                            + w10 * v10 + w11 * vb[j][sx].y;
                }
            }
        }
    }

    // out[(k*256 + c2 + j*64)*49 + p] = k*12544 + j*3136 + pair
    // pair = g*64+lane -> consecutive lanes store consecutive addresses.
    size_t ob = (size_t)k * (NUM_CH * 49) + (size_t)g * 64 + lane;
    #pragma unroll
    for (int j = 0; j < CPT; ++j)
        out[ob + (size_t)j * PAIRS] = acc[j];
}

extern "C" void kernel_launch(void* const* d_in, const int* in_sizes, int n_in,
                              void* d_out, int out_size, void* d_ws, size_t ws_size,
                              hipStream_t stream) {
    const float* f0   = (const float*)d_in[0];
    const float* f1   = (const float*)d_in[1];
    const float* f2   = (const float*)d_in[2];
    const float* f3   = (const float*)d_in[3];
    const float* rois = (const float*)d_in[4];
    // d_in[5] = rois_counts (unused)
    const int* level = (const int*)d_in[6];
    float* out = (float*)d_out;

    int K  = out_size / (NUM_CH * 49);   // rois
    int NW = K * WPR;                    // one wave per (pair-group, roi)
    int threads = 256;                   // 4 waves per block
    int blocks  = (NW + 3) / 4;
    roi_align_kernel<<<blocks, threads, 0, stream>>>(f0, f1, f2, f3, rois, level, out, K, NW);
}